// Round 1
// baseline (466.982 us; speedup 1.0000x reference)
//
#include <hip/hip_runtime.h>
#include <hip/hip_bf16.h>

// out = x*a + (1-a)*b, all float32, elementwise over 134,217,728 elements.
// Memory-bound: 16 B/elem HBM traffic, target ~6.3 TB/s achievable BW.

__global__ __launch_bounds__(256) void SaltAndPepper_72834055405766_kernel(
    const float4* __restrict__ x,
    const float4* __restrict__ a,
    const float4* __restrict__ b,
    float4* __restrict__ out,
    long n4)
{
    long i = (long)blockIdx.x * blockDim.x + threadIdx.x;
    const long stride = (long)gridDim.x * blockDim.x;
    for (; i < n4; i += stride) {
        const float4 xv = x[i];
        const float4 av = a[i];
        const float4 bv = b[i];
        float4 o;
        o.x = xv.x * av.x + (1.0f - av.x) * bv.x;
        o.y = xv.y * av.y + (1.0f - av.y) * bv.y;
        o.z = xv.z * av.z + (1.0f - av.z) * bv.z;
        o.w = xv.w * av.w + (1.0f - av.w) * bv.w;
        out[i] = o;
    }
}

// Scalar tail kernel (not needed for n % 4 == 0, kept for generality).
__global__ void SaltAndPepper_tail_kernel(
    const float* __restrict__ x,
    const float* __restrict__ a,
    const float* __restrict__ b,
    float* __restrict__ out,
    long start, long n)
{
    long i = start + (long)blockIdx.x * blockDim.x + threadIdx.x;
    if (i < n) {
        const float av = a[i];
        out[i] = x[i] * av + (1.0f - av) * b[i];
    }
}

extern "C" void kernel_launch(void* const* d_in, const int* in_sizes, int n_in,
                              void* d_out, int out_size, void* d_ws, size_t ws_size,
                              hipStream_t stream) {
    const float* x = (const float*)d_in[0];
    const float* a = (const float*)d_in[1];
    const float* b = (const float*)d_in[2];
    float* out = (float*)d_out;

    const long n  = (long)out_size;     // 134,217,728
    const long n4 = n / 4;              // vectorized count
    const long tail_start = n4 * 4;

    const int block = 256;
    long blocks_needed = (n4 + block - 1) / block;
    int grid = (int)(blocks_needed < 2048 ? blocks_needed : 2048);

    SaltAndPepper_72834055405766_kernel<<<grid, block, 0, stream>>>(
        (const float4*)x, (const float4*)a, (const float4*)b, (float4*)out, n4);

    if (tail_start < n) {
        long tail = n - tail_start;
        int tgrid = (int)((tail + block - 1) / block);
        SaltAndPepper_tail_kernel<<<tgrid, block, 0, stream>>>(
            x, a, b, out, tail_start, n);
    }
}

// Round 2
// 382.376 us; speedup vs baseline: 1.2213x; 1.2213x over previous
//
#include <hip/hip_runtime.h>
#include <hip/hip_bf16.h>

// out = x*a + (1-a)*b, all float32, 134,217,728 elements.
// Memory-bound streaming op. Strategy: exact grid, unroll-by-4 float4 per
// thread (12 independent loads in flight) for max memory-level parallelism.

#define UNROLL 4

__global__ __launch_bounds__(256) void SaltAndPepper_72834055405766_kernel(
    const float4* __restrict__ x,
    const float4* __restrict__ a,
    const float4* __restrict__ b,
    float4* __restrict__ out,
    long n4)
{
    // Each block owns a contiguous span of 256*UNROLL float4s; thread t
    // touches base+t, base+t+256, ... (coalesced within each unroll step).
    const long base = (long)blockIdx.x * (blockDim.x * UNROLL) + threadIdx.x;

    float4 xv[UNROLL], av[UNROLL], bv[UNROLL];

    // Fast path: full tile (true for all blocks given n4 % (256*UNROLL) == 0).
    if (base + (UNROLL - 1) * 256 < n4) {
#pragma unroll
        for (int k = 0; k < UNROLL; ++k) xv[k] = x[base + k * 256];
#pragma unroll
        for (int k = 0; k < UNROLL; ++k) av[k] = a[base + k * 256];
#pragma unroll
        for (int k = 0; k < UNROLL; ++k) bv[k] = b[base + k * 256];
#pragma unroll
        for (int k = 0; k < UNROLL; ++k) {
            float4 o;
            o.x = xv[k].x * av[k].x + (1.0f - av[k].x) * bv[k].x;
            o.y = xv[k].y * av[k].y + (1.0f - av[k].y) * bv[k].y;
            o.z = xv[k].z * av[k].z + (1.0f - av[k].z) * bv[k].z;
            o.w = xv[k].w * av[k].w + (1.0f - av[k].w) * bv[k].w;
            out[base + k * 256] = o;
        }
    } else {
#pragma unroll
        for (int k = 0; k < UNROLL; ++k) {
            const long i = base + k * 256;
            if (i < n4) {
                const float4 xs = x[i], as = a[i], bs = b[i];
                float4 o;
                o.x = xs.x * as.x + (1.0f - as.x) * bs.x;
                o.y = xs.y * as.y + (1.0f - as.y) * bs.y;
                o.z = xs.z * as.z + (1.0f - as.z) * bs.z;
                o.w = xs.w * as.w + (1.0f - as.w) * bs.w;
                out[i] = o;
            }
        }
    }
}

extern "C" void kernel_launch(void* const* d_in, const int* in_sizes, int n_in,
                              void* d_out, int out_size, void* d_ws, size_t ws_size,
                              hipStream_t stream) {
    const float* x = (const float*)d_in[0];
    const float* a = (const float*)d_in[1];
    const float* b = (const float*)d_in[2];
    float* out = (float*)d_out;

    const long n  = (long)out_size;      // 134,217,728
    const long n4 = n / 4;               // 33,554,432 float4s (n % 4 == 0)

    const int block = 256;
    const long per_block = (long)block * UNROLL;           // 1024 float4s
    const long grid = (n4 + per_block - 1) / per_block;    // 32768 blocks

    SaltAndPepper_72834055405766_kernel<<<(int)grid, block, 0, stream>>>(
        (const float4*)x, (const float4*)a, (const float4*)b, (float4*)out, n4);
}

// Round 3
// 351.734 us; speedup vs baseline: 1.3277x; 1.0871x over previous
//
#include <hip/hip_runtime.h>
#include <hip/hip_bf16.h>

// out = x*a + (1-a)*b, all float32, 134,217,728 elements.
// Memory-bound streaming op (3R + 1W = 16 B/elem, 2.147 GB total).
// Strategy: exact grid, unroll-by-4 float4 per thread (12 independent loads
// in flight), nontemporal hints on all streams to avoid L2/LLC retention tax.

#define UNROLL 4

typedef float f32x4 __attribute__((ext_vector_type(4)));

__global__ __launch_bounds__(256) void SaltAndPepper_72834055405766_kernel(
    const f32x4* __restrict__ x,
    const f32x4* __restrict__ a,
    const f32x4* __restrict__ b,
    f32x4* __restrict__ out,
    long n4)
{
    // Each block owns a contiguous span of 256*UNROLL float4s; thread t
    // touches base+t, base+t+256, ... (coalesced within each unroll step).
    const long base = (long)blockIdx.x * (blockDim.x * UNROLL) + threadIdx.x;

    f32x4 xv[UNROLL], av[UNROLL], bv[UNROLL];

    if (base + (UNROLL - 1) * 256 < n4) {
#pragma unroll
        for (int k = 0; k < UNROLL; ++k)
            xv[k] = __builtin_nontemporal_load(&x[base + k * 256]);
#pragma unroll
        for (int k = 0; k < UNROLL; ++k)
            av[k] = __builtin_nontemporal_load(&a[base + k * 256]);
#pragma unroll
        for (int k = 0; k < UNROLL; ++k)
            bv[k] = __builtin_nontemporal_load(&b[base + k * 256]);
#pragma unroll
        for (int k = 0; k < UNROLL; ++k) {
            f32x4 o = xv[k] * av[k] + (1.0f - av[k]) * bv[k];
            __builtin_nontemporal_store(o, &out[base + k * 256]);
        }
    } else {
#pragma unroll
        for (int k = 0; k < UNROLL; ++k) {
            const long i = base + k * 256;
            if (i < n4) {
                const f32x4 xs = x[i], as = a[i], bs = b[i];
                f32x4 o = xs * as + (1.0f - as) * bs;
                out[i] = o;
            }
        }
    }
}

extern "C" void kernel_launch(void* const* d_in, const int* in_sizes, int n_in,
                              void* d_out, int out_size, void* d_ws, size_t ws_size,
                              hipStream_t stream) {
    const float* x = (const float*)d_in[0];
    const float* a = (const float*)d_in[1];
    const float* b = (const float*)d_in[2];
    float* out = (float*)d_out;

    const long n  = (long)out_size;      // 134,217,728
    const long n4 = n / 4;               // 33,554,432 float4s (n % 4 == 0)

    const int block = 256;
    const long per_block = (long)block * UNROLL;           // 1024 float4s
    const long grid = (n4 + per_block - 1) / per_block;    // 32768 blocks

    SaltAndPepper_72834055405766_kernel<<<(int)grid, block, 0, stream>>>(
        (const f32x4*)x, (const f32x4*)a, (const f32x4*)b, (f32x4*)out, n4);
}